// Round 6
// baseline (337.952 us; speedup 1.0000x reference)
//
#include <hip/hip_runtime.h>
#include <hip/hip_fp16.h>
#include <math.h>

// Problem constants
#define B_     4
#define CIN    128
#define LEN    2048
#define DMODEL 256
#define DSTATE 16
#define NHEADS 256
#define DINNER 768
#define CONVDIM 800      // DINNER + 2*DSTATE
#define DINPROJ 1824     // 2*DINNER + 2*DSTATE + NHEADS
#define EPS_   1e-5f
#define CHUNK  64
#define NCHUNK 32        // LEN / CHUNK

typedef _Float16 f16x8 __attribute__((ext_vector_type(8)));
typedef float    f32x4 __attribute__((ext_vector_type(4)));

__device__ __forceinline__ float silu_(float x){ return x / (1.0f + __expf(-x)); }
__device__ __forceinline__ float softplus_(float x){
    return x > 0.f ? x + log1pf(__expf(-x)) : log1pf(__expf(x));
}

// async global->LDS, 16B per lane; LDS dest = wave-uniform base + lane*16
__device__ __forceinline__ void gl2lds16(const _Float16* g, _Float16* l){
    __builtin_amdgcn_global_load_lds(
        (const __attribute__((address_space(1))) void*)g,
        (__attribute__((address_space(3))) void*)l, 16, 0, 0);
}

// ---------------------------------------------------------------------------
// fp32 -> fp16 convert of the three weight tensors, one dispatch
// ---------------------------------------------------------------------------
__global__ __launch_bounds__(256) void k_f2h3(const float* __restrict__ a0,
                                              const float* __restrict__ a1,
                                              const float* __restrict__ a2,
                                              _Float16* __restrict__ o0,
                                              _Float16* __restrict__ o1,
                                              _Float16* __restrict__ o2,
                                              int n0, int n1, int n2){
    int total = n0 + n1 + n2;
    for (int i = blockIdx.x * 256 + threadIdx.x; i < total; i += gridDim.x * 256){
        if (i < n0)            o0[i] = (_Float16)a0[i];
        else if (i < n0 + n1)  o1[i - n0] = (_Float16)a1[i - n0];
        else                   o2[i - n0 - n1] = (_Float16)a2[i - n0 - n1];
    }
}

// ---------------------------------------------------------------------------
// im2col for the conv projection: xcol[(b,l)][(ci,k)] = x[b,ci,l-1+k], fp16.
// ---------------------------------------------------------------------------
__global__ __launch_bounds__(256) void k_im2col(const float* __restrict__ x,
                                                _Float16* __restrict__ xcol){
    __shared__ float xs[CIN][68];      // 67 used
    int blk = blockIdx.x;              // 0..127
    int b  = blk >> 5;
    int l0 = (blk & 31) << 6;          // *64
    const float* xb = x + (size_t)b * CIN * LEN;
    for (int idx = threadIdx.x; idx < CIN * 67; idx += 256){
        int ci = idx / 67, j = idx % 67;
        int gl = l0 - 1 + j;
        xs[ci][j] = (gl >= 0 && gl < LEN) ? xb[ci * LEN + gl] : 0.f;
    }
    __syncthreads();
    #pragma unroll
    for (int v = 0; v < 16; v++){
        int id = v * 256 + threadIdx.x;   // 0..4095
        int rl = id >> 6, c = id & 63;    // row-in-tile, 16B chunk
        f16x8 pk;
        #pragma unroll
        for (int e = 0; e < 8; e++){
            int ci = c * 2 + (e >> 2), k = e & 3;
            pk[e] = (_Float16)xs[ci][rl + k];
        }
        *(f16x8*)&xcol[((size_t)(b * LEN + l0 + rl)) * 512 + c * 8] = pk;
    }
}

// ---------------------------------------------------------------------------
// Shared MFMA GEMM: C[M][N] = A[M][K] . Bw[N][K]^T, f16 inputs, fp32 acc.
// 128x128 tile, BK=32, 4 waves (2x2), each wave 4x4 mfma_f32_16x16x32_f16.
// EPI 0: u_h fp16; EPI 1: split z/xbc/dt(+softplus); EPI 2: fp32 (B,D,L).
// ---------------------------------------------------------------------------
template<int K, int EPI>
__global__ __launch_bounds__(256) void k_gemm(const _Float16* __restrict__ A,
                                              const _Float16* __restrict__ Bw,
                                              const float* __restrict__ dt_bias,
                                              _Float16* __restrict__ o_u,
                                              _Float16* __restrict__ o_z,
                                              _Float16* __restrict__ o_xbc,
                                              _Float16* __restrict__ o_dt,
                                              float* __restrict__ o_f){
    __shared__ __align__(16) _Float16 As[128 * 32];
    __shared__ __align__(16) _Float16 Bs[128 * 32];
    int tid  = threadIdx.x;
    int wv   = tid >> 6;
    int lane = tid & 63;
    int quad = lane >> 4;
    int l16  = lane & 15;
    int m0 = blockIdx.x * 128;
    int n0 = blockIdx.y * 128;
    int wm = (wv >> 1) * 64;
    int wn = (wv & 1) * 64;
    int srow = lane >> 2;              // 0..15 staging row
    int scol = (lane & 3) * 8;         // halves offset 0,8,16,24

    f32x4 acc[4][4];
    #pragma unroll
    for (int i = 0; i < 4; i++)
        #pragma unroll
        for (int j = 0; j < 4; j++)
            acc[i][j] = (f32x4){0.f, 0.f, 0.f, 0.f};

    for (int k0 = 0; k0 < K; k0 += 32){
        #pragma unroll
        for (int j = 0; j < 2; j++){
            int ar = m0 + wv * 32 + j * 16 + srow;
            gl2lds16(A + (size_t)ar * K + k0 + scol,
                     &As[(wv * 32 + j * 16) * 32]);
            int nr = n0 + wv * 32 + j * 16 + srow;
            if (EPI == 1) nr = nr > (DINPROJ - 1) ? (DINPROJ - 1) : nr;
            gl2lds16(Bw + (size_t)nr * K + k0 + scol,
                     &Bs[(wv * 32 + j * 16) * 32]);
        }
        __syncthreads();
        f16x8 af[4], bf[4];
        #pragma unroll
        for (int i = 0; i < 4; i++)
            af[i] = *(const f16x8*)&As[(wm + i * 16 + l16) * 32 + quad * 8];
        #pragma unroll
        for (int j = 0; j < 4; j++)
            bf[j] = *(const f16x8*)&Bs[(wn + j * 16 + l16) * 32 + quad * 8];
        #pragma unroll
        for (int i = 0; i < 4; i++)
            #pragma unroll
            for (int j = 0; j < 4; j++)
                acc[i][j] = __builtin_amdgcn_mfma_f32_16x16x32_f16(
                                af[i], bf[j], acc[i][j], 0, 0, 0);
        __syncthreads();
    }

    if (EPI == 0){
        #pragma unroll
        for (int j = 0; j < 4; j++){
            int col = n0 + wn + j * 16 + l16;
            #pragma unroll
            for (int i = 0; i < 4; i++){
                int row = m0 + wm + i * 16 + quad * 4;
                #pragma unroll
                for (int r = 0; r < 4; r++)
                    o_u[(size_t)(row + r) * DMODEL + col] = (_Float16)acc[i][j][r];
            }
        }
    } else if (EPI == 1){
        #pragma unroll
        for (int j = 0; j < 4; j++){
            int col = n0 + wn + j * 16 + l16;
            if (col < DINNER){
                #pragma unroll
                for (int i = 0; i < 4; i++){
                    int row = m0 + wm + i * 16 + quad * 4;
                    #pragma unroll
                    for (int r = 0; r < 4; r++)
                        o_z[(size_t)(row + r) * DINNER + col] = (_Float16)acc[i][j][r];
                }
            } else if (col < DINNER + CONVDIM){
                int cc = col - DINNER;
                #pragma unroll
                for (int i = 0; i < 4; i++){
                    int row = m0 + wm + i * 16 + quad * 4;
                    #pragma unroll
                    for (int r = 0; r < 4; r++)
                        o_xbc[(size_t)(row + r) * CONVDIM + cc] = (_Float16)acc[i][j][r];
                }
            } else if (col < DINPROJ){
                int hh = col - (DINNER + CONVDIM);
                float bias = dt_bias[hh];
                #pragma unroll
                for (int i = 0; i < 4; i++){
                    int row = m0 + wm + i * 16 + quad * 4;
                    #pragma unroll
                    for (int r = 0; r < 4; r++)
                        o_dt[(size_t)(row + r) * NHEADS + hh] =
                            (_Float16)softplus_(acc[i][j][r] + bias);
                }
            }
        }
    } else {
        #pragma unroll
        for (int i = 0; i < 4; i++){
            int row = m0 + wm + i * 16 + quad * 4;
            int b = row >> 11, l = row & (LEN - 1);
            #pragma unroll
            for (int j = 0; j < 4; j++){
                int d = n0 + wn + j * 16 + l16;
                *(f32x4*)&o_f[(((size_t)(b * DMODEL + d)) << 11) + l] = acc[i][j];
            }
        }
    }
}

// ---------------------------------------------------------------------------
// depthwise causal conv (4-tap) + bias + SiLU, fp16 in/out.
// ---------------------------------------------------------------------------
__global__ __launch_bounds__(256) void k_dwconv(const __half* __restrict__ xbc,
                                                const float* __restrict__ cw,
                                                const float* __restrict__ cb,
                                                __half* __restrict__ xcc){
    int idx = blockIdx.x * 256 + threadIdx.x;   // < 8192*800
    int c = idx % CONVDIM;
    int r = idx / CONVDIM;
    int l = r & (LEN - 1);
    float4 wv = *(const float4*)(cw + c * 4);
    float acc = cb[c];
    if (l >= 3){
        const __half* base = xbc + (size_t)(r - 3) * CONVDIM + c;
        acc += __half2float(base[0]) * wv.x + __half2float(base[CONVDIM]) * wv.y +
               __half2float(base[2 * CONVDIM]) * wv.z + __half2float(base[3 * CONVDIM]) * wv.w;
    } else {
        const float wk[4] = {wv.x, wv.y, wv.z, wv.w};
        for (int k = 0; k < 4; k++){
            int t = l - 3 + k;
            if (t >= 0) acc += __half2float(xbc[(size_t)(r + k - 3) * CONVDIM + c]) * wk[k];
        }
    }
    xcc[idx] = __float2half(silu_(acc));
}

// ---------------------------------------------------------------------------
// k_scanAC: per (b, head-group, chunk): recurrence from ZERO state.
// Writes y_local (incl. D_skip*x) per step via shfl reduction, plus the
// chunk-final local state (fp16) and chunk decay exp(A*sum(dt)).
// y is later corrected by k_fixup: y += decay_t * (C_t . h_init)  (linearity).
// ---------------------------------------------------------------------------
__global__ __launch_bounds__(64) void k_scanAC(const __half* __restrict__ dtb,
                                               const __half* __restrict__ xcc,
                                               const float* __restrict__ A_log,
                                               const float* __restrict__ D_skip,
                                               __half* __restrict__ y,
                                               __half* __restrict__ cstate,
                                               float* __restrict__ dsum){
    int blk = blockIdx.x;              // 0..8191
    int c  = blk & (NCHUNK - 1);
    int hg = (blk >> 5) & 63;
    int b  = blk >> 11;
    int lane = threadIdx.x;
    int hl = lane >> 4;
    int n  = lane & 15;
    int h  = hg * 4 + hl;
    int c0 = h * 3;
    float A   = -__expf(A_log[h]);
    float Dsk = D_skip[h];
    int t0 = c * CHUNK;
    const __half* xr  = xcc + ((size_t)b * LEN + t0) * CONVDIM;
    const __half* dtp = dtb + ((size_t)b * LEN + t0) * NHEADS + h;
    float h0 = 0.f, h1 = 0.f, h2 = 0.f, sdt = 0.f;
    __half* yp = y + ((size_t)b * LEN + t0) * DINNER + c0;
    for (int t = 0; t < CHUNK; t++){
        float vx0 = __half2float(xr[c0]);
        float vx1 = __half2float(xr[c0 + 1]);
        float vx2 = __half2float(xr[c0 + 2]);
        float vB  = __half2float(xr[DINNER + n]);
        float vC  = __half2float(xr[DINNER + DSTATE + n]);
        float cdt = __half2float(dtp[(size_t)t * NHEADS]);
        float dA  = __expf(cdt * A);
        float dtB = cdt * vB;
        h0 = fmaf(h0, dA, vx0 * dtB);
        h1 = fmaf(h1, dA, vx1 * dtB);
        h2 = fmaf(h2, dA, vx2 * dtB);
        sdt += cdt;
        float p0 = h0 * vC, p1 = h1 * vC, p2 = h2 * vC;
        #pragma unroll
        for (int m = 1; m < 16; m <<= 1){
            p0 += __shfl_xor(p0, m, 64);
            p1 += __shfl_xor(p1, m, 64);
            p2 += __shfl_xor(p2, m, 64);
        }
        if (n < 3){
            float pv = (n == 0) ? p0 : ((n == 1) ? p1 : p2);
            float xv = (n == 0) ? vx0 : ((n == 1) ? vx1 : vx2);
            yp[n] = __float2half(fmaf(Dsk, xv, pv));
        }
        xr += CONVDIM;
        yp += DINNER;
    }
    size_t sbase = (((size_t)(b * NHEADS + h)) * NCHUNK + c) * 48;
    cstate[sbase + n]      = __float2half(h0);
    cstate[sbase + 16 + n] = __float2half(h1);
    cstate[sbase + 32 + n] = __float2half(h2);
    if (n == 0) dsum[(size_t)(b * NHEADS + h) * NCHUNK + c] = __expf(A * sdt);
}

// ---------------------------------------------------------------------------
// scan pass B: per (b,h), combine chunk summaries sequentially; overwrite
// cstate[c] in place with the INITIAL state of chunk c.
// ---------------------------------------------------------------------------
__global__ __launch_bounds__(64) void k_scanB(__half* __restrict__ cstate,
                                              const float* __restrict__ dsum){
    int bh = blockIdx.x;               // 0..1023
    int lane = threadIdx.x;
    if (lane >= 48) return;
    __half* st = cstate + (size_t)bh * NCHUNK * 48 + lane;
    const float* dd = dsum + (size_t)bh * NCHUNK;
    float H = 0.f;
    for (int c = 0; c < NCHUNK; c++){
        float d = dd[c];
        float s = __half2float(st[(size_t)c * 48]);
        st[(size_t)c * 48] = __float2half(H);
        H = fmaf(H, d, s);
    }
}

// ---------------------------------------------------------------------------
// k_fixup: fully parallel correction. One wave per (b,h,chunk); lane = t.
// cum_t = inclusive prefix of dt within chunk (6-stage shfl);
// y[t,p] += exp(A*cum_t) * sum_n C[t,n]*h_init[n,p].
// ---------------------------------------------------------------------------
__global__ __launch_bounds__(256) void k_fixup(const __half* __restrict__ dtb,
                                               const __half* __restrict__ xcc,
                                               const float* __restrict__ A_log,
                                               const __half* __restrict__ cstate,
                                               __half* __restrict__ y){
    int task = blockIdx.x * 4 + (threadIdx.x >> 6);   // 0..32767
    int lane = threadIdx.x & 63;                      // = t
    int c = task & (NCHUNK - 1);
    int h = (task >> 5) & (NHEADS - 1);
    int b = task >> 13;
    float A = -__expf(A_log[h]);
    size_t row = (size_t)b * LEN + c * CHUNK + lane;
    // inclusive prefix sum of dt over the 64 lanes
    float cum = __half2float(dtb[row * NHEADS + h]);
    #pragma unroll
    for (int m = 1; m < 64; m <<= 1){
        float v = __shfl(cum, lane - m, 64);
        if (lane >= m) cum += v;
    }
    float decay = __expf(A * cum);
    // C[t, 0..15]
    const _Float16* cp = (const _Float16*)(xcc) + row * CONVDIM + DINNER + DSTATE;
    f16x8 cv0 = *(const f16x8*)cp;
    f16x8 cv1 = *(const f16x8*)(cp + 8);
    // h_init[3][16] (wave-uniform address)
    const _Float16* hp = (const _Float16*)(cstate) + (size_t)task * 48;
    f16x8 hv[6];
    #pragma unroll
    for (int i = 0; i < 6; i++) hv[i] = *(const f16x8*)(hp + i * 8);
    float s0 = 0.f, s1 = 0.f, s2 = 0.f;
    #pragma unroll
    for (int e = 0; e < 8; e++){
        float cl = (float)cv0[e], ch = (float)cv1[e];
        s0 = fmaf(cl, (float)hv[0][e], s0); s0 = fmaf(ch, (float)hv[1][e], s0);
        s1 = fmaf(cl, (float)hv[2][e], s1); s1 = fmaf(ch, (float)hv[3][e], s1);
        s2 = fmaf(cl, (float)hv[4][e], s2); s2 = fmaf(ch, (float)hv[5][e], s2);
    }
    __half* yp = y + row * DINNER + h * 3;
    yp[0] = __float2half(__half2float(yp[0]) + decay * s0);
    yp[1] = __float2half(__half2float(yp[1]) + decay * s1);
    yp[2] = __float2half(__half2float(yp[2]) + decay * s2);
}

// ---------------------------------------------------------------------------
// gated RMSNorm (in place on y, fp16 storage, fp32 math)
// ---------------------------------------------------------------------------
__global__ __launch_bounds__(256) void k_norm(__half* __restrict__ y,
                                              const __half* __restrict__ z,
                                              const float* __restrict__ nw){
    __shared__ float wsum[4];
    size_t r = blockIdx.x;
    int tid = threadIdx.x;
    const __half* zr = z + r * DINNER;
    __half* yr = y + r * DINNER;
    int e0 = tid, e1 = tid + 256, e2 = tid + 512;
    float t0 = __half2float(yr[e0]) * silu_(__half2float(zr[e0]));
    float t1 = __half2float(yr[e1]) * silu_(__half2float(zr[e1]));
    float t2 = __half2float(yr[e2]) * silu_(__half2float(zr[e2]));
    float ss = t0 * t0 + t1 * t1 + t2 * t2;
    #pragma unroll
    for (int m = 1; m < 64; m <<= 1) ss += __shfl_xor(ss, m, 64);
    if ((tid & 63) == 0) wsum[tid >> 6] = ss;
    __syncthreads();
    float tot = wsum[0] + wsum[1] + wsum[2] + wsum[3];
    float sc = rsqrtf(tot / (float)DINNER + EPS_);
    yr[e0] = __float2half(t0 * sc * nw[e0]);
    yr[e1] = __float2half(t1 * sc * nw[e1]);
    yr[e2] = __float2half(t2 * sc * nw[e2]);
}

// ---------------------------------------------------------------------------
extern "C" void kernel_launch(void* const* d_in, const int* in_sizes, int n_in,
                              void* d_out, int out_size, void* d_ws, size_t ws_size,
                              hipStream_t stream) {
    const float* x          = (const float*)d_in[0];
    const float* proj_w     = (const float*)d_in[1];
    const float* in_proj_w  = (const float*)d_in[2];
    const float* conv_w     = (const float*)d_in[3];
    const float* conv_b     = (const float*)d_in[4];
    const float* dt_bias    = (const float*)d_in[5];
    const float* A_log      = (const float*)d_in[6];
    const float* D_skip     = (const float*)d_in[7];
    const float* norm_w     = (const float*)d_in[8];
    const float* out_proj_w = (const float*)d_in[9];
    float* out = (float*)d_out;

    // fp16 proj/in_proj weights live in d_out (dead until the final GEMM
    // overwrites all of d_out with the result).
    char* ob = (char*)d_out;
    _Float16* pw_h  = (_Float16*)ob;                   //   262,144 B (256x512)
    _Float16* ipw_h = (_Float16*)(ob + 262144);        //   933,888 B (1824x256)

    // Workspace (bytes), total 46,661,632 (~44.5 MiB, <= 48.9 MiB known-good):
    char* wsb = (char*)d_ws;
    _Float16* xcol  = (_Float16*)(wsb);                // 8192x512 fp16
    _Float16* u_h   = (_Float16*)(wsb + 8388608);      // 8192x256 fp16
    __half*   xcc_h = (__half*)(wsb);                  // 8192x800 fp16 (alias)
    __half*   z_h   = (__half*)(wsb + 13107200);       // 8192x768
    __half*   xbc_h = (__half*)(wsb + 25690112);       // 8192x800
    __half*   y_h   = xbc_h;                           // alias: xbc dead after dwconv
    __half*   dt_h  = (__half*)(wsb + 38797312);       // 8192x256
    __half*   cstate= (__half*)(wsb + 42991616);       // B*NH*NCHUNK*48
    float*    dsum  = (float*)(wsb + 46137344);        // B*NH*NCHUNK
    _Float16* opw_h = (_Float16*)(wsb + 46268416);     // 256x768 fp16

    k_f2h3  <<<96, 256, 0, stream>>>(proj_w, in_proj_w, out_proj_w,
                                     pw_h, ipw_h, opw_h,
                                     DMODEL * CIN * 4, DINPROJ * DMODEL,
                                     DMODEL * DINNER);
    k_im2col<<<128, 256, 0, stream>>>(x, xcol);
    k_gemm<512, 0><<<dim3(64, 2), 256, 0, stream>>>(xcol, pw_h, nullptr,
        u_h, nullptr, nullptr, nullptr, nullptr);
    k_gemm<256, 1><<<dim3(64, 15), 256, 0, stream>>>(u_h, ipw_h, dt_bias,
        nullptr, (_Float16*)z_h, (_Float16*)xbc_h, (_Float16*)dt_h, nullptr);
    k_dwconv<<<25600, 256, 0, stream>>>(xbc_h, conv_w, conv_b, xcc_h);
    k_scanAC<<<8192, 64, 0, stream>>>(dt_h, xcc_h, A_log, D_skip, y_h, cstate, dsum);
    k_scanB <<<1024, 64, 0, stream>>>(cstate, dsum);
    k_fixup <<<8192, 256, 0, stream>>>(dt_h, xcc_h, A_log, cstate, y_h);
    k_norm  <<<8192, 256, 0, stream>>>(y_h, z_h, norm_w);
    k_gemm<768, 2><<<dim3(64, 2), 256, 0, stream>>>((const _Float16*)y_h, opw_h,
        nullptr, nullptr, nullptr, nullptr, nullptr, out);
}